// Round 23
// baseline (895.687 us; speedup 1.0000x reference)
//
#include <hip/hip_runtime.h>
#include <hip/hip_bf16.h>

#define V_ 16000
#define L_ 12
#define K_ 512
#define LOST_ 512
#define D_ 128

constexpr float CW = 0.5f;
constexpr float IDC = 3.5f;

typedef __attribute__((ext_vector_type(8))) short bf16x8;
typedef __attribute__((ext_vector_type(4))) float f32x4;

__device__ __align__(16) float g_lost[LOST_ * D_];    // lost_unit_emb f32 [512][128]
__device__ __align__(16) short g_lost_bf[LOST_ * D_]; // bf16 copy, [m][d] k-contiguous
__device__ __align__(16) float g_ulp[K_ * LOST_];     // unit_log_probs [512][512]
__device__ __align__(16) short g_wcv[2 * 128 * 384];  // conv weights bf16 [c][dout][t3*128+di]

__device__ __forceinline__ short f2b(float x) {
    __hip_bfloat16 h = __float2bfloat16(x);
    return *reinterpret_cast<short*>(&h);
}

// ---------------- kernel 0: repack conv weights -> bf16 [c][dout][k], k=t3*128+di
__global__ __launch_bounds__(256) void k_wcv(const float* __restrict__ wA,
                                             const float* __restrict__ wB) {
    int idx = blockIdx.x * 256 + threadIdx.x;
    if (idx >= 2 * 128 * 384) return;
    int di = idx % 128;
    int t3 = (idx / 128) % 3;
    int dout = (idx / 384) % 128;
    int c = idx / (128 * 384);
    const float* w = c ? wB : wA;
    g_wcv[idx] = f2b(w[((size_t)dout * 128 + di) * 3 + t3]);
}

// ---------------- kernel 1: lost_emb = aligner @ E (f32 + bf16)
__global__ __launch_bounds__(128) void k_lost(const float* __restrict__ W,
                                              const float* __restrict__ E) {
    int m = blockIdx.x;
    int d = threadIdx.x;
    const float* wrow = W + (size_t)m * K_;
    float acc = 0.f;
    for (int k = 0; k < K_; ++k) acc = fmaf(wrow[k], E[k * D_ + d], acc);
    g_lost[m * D_ + d] = acc;
    g_lost_bf[m * D_ + d] = f2b(acc);
}

// ---------------- kernel 2: unit_log_probs + alignment output (f32)
__global__ __launch_bounds__(512) void k_ulp(const float* __restrict__ E,
                                             float* __restrict__ align_out) {
    int k = blockIdx.x, t = threadIdx.x;
    __shared__ float e[D_];
    __shared__ float red[8];
    if (t < D_) e[t] = E[k * D_ + t];
    __syncthreads();
    const float* lm = g_lost + (size_t)t * D_;
    float acc = 0.f;
    for (int d = 0; d < D_; d += 4) {
        float4 lv = *(const float4*)(lm + d);
        acc = fmaf(e[d], lv.x, acc);
        acc = fmaf(e[d + 1], lv.y, acc);
        acc = fmaf(e[d + 2], lv.z, acc);
        acc = fmaf(e[d + 3], lv.w, acc);
    }
    int lane = t & 63, wid = t >> 6;
    float wm = acc;
    for (int off = 32; off; off >>= 1) wm = fmaxf(wm, __shfl_xor(wm, off, 64));
    if (lane == 0) red[wid] = wm;
    __syncthreads();
    float bm = red[0];
#pragma unroll
    for (int i = 1; i < 8; ++i) bm = fmaxf(bm, red[i]);
    __syncthreads();
    float s = expf(acc - bm);
    for (int off = 32; off; off >>= 1) s += __shfl_xor(s, off, 64);
    if (lane == 0) red[wid] = s;
    __syncthreads();
    float bs = 0.f;
#pragma unroll
    for (int i = 0; i < 8; ++i) bs += red[i];
    float lp = acc - bm - logf(bs);
    g_ulp[(size_t)k * LOST_ + t] = lp;
    align_out[(size_t)k * LOST_ + t] = expf(lp);
}

// swizzled column: keep low 3 bits, XOR granule (bits 3..6) with row&7
__device__ __forceinline__ int swz(int col, int row) {
    return (col & 7) | ((((col >> 3) ^ (row & 7)) & 15) << 3);
}

// ---------------- kernel 3: fused MFMA per-v kernel; 3 blocks/CU register budget
__global__ __launch_bounds__(256, 3) void k_main(const float* __restrict__ E,
                                                 const float* __restrict__ bA,
                                                 const float* __restrict__ bB,
                                                 const int* __restrict__ ids,
                                                 const int* __restrict__ lens,
                                                 float* __restrict__ sub_out,
                                                 float* __restrict__ ins_out) {
    __shared__ __align__(16) char shbuf[24 * 516 * 4];    // 49536 B arena
    short (*emb_bf)[128] = (short(*)[128])shbuf;          // 18 rows
    short (*ctx_bf)[128] = (short(*)[128])(shbuf + 4608); // 32 rows
    float (*stage)[516] = (float(*)[516])shbuf;           // 24 f32 rows (epilogue)
    __shared__ float redm[4][16];
    __shared__ float reds[4][16];
    __shared__ int sids[12];
    __shared__ int slen;

    int v = blockIdx.x;
    int t = threadIdx.x;
    int lane = t & 63, w = t >> 6;
    int l15 = lane & 15, kg = lane >> 4;

    if (t < 12) sids[t] = min(max(ids[v * 12 + t], 0), 511);
    if (t == 12) slen = min(max(lens[v], 0), 12);
    for (int i = t; i < 8 * 128; i += 256) ctx_bf[24 + (i >> 7)][i & 127] = 0;
    __syncthreads();
    int len = slen;

    // ---- gather masked emb rows -> bf16 swizzled LDS
    for (int i = t; i < 18 * 128; i += 256) {
        int row = i >> 7, di = i & 127;
        float val = 0.f;
        if (row >= 1 && row <= 12) {
            int pos = row - 1;
            if (pos < len) val = E[(size_t)sids[pos] * D_ + di];
        }
        emb_bf[row][swz(di, row)] = f2b(val);
    }
    __syncthreads();

    // ---- conv via MFMA: wave w -> c = w&1, dout-tiles dtb..dtb+3
    {
        int c = w & 1;
        int dtb = (w >> 1) * 4;
        f32x4 acc[4];
#pragma unroll
        for (int i = 0; i < 4; ++i) acc[i] = (f32x4){0.f, 0.f, 0.f, 0.f};
        const short* wb = g_wcv + (size_t)c * 128 * 384;
#pragma unroll
        for (int kk = 0; kk < 12; ++kk) {
            int t3 = kk >> 2;
            int row = l15 + t3;
            int g = (((kk & 3) * 4 + kg) ^ (row & 7)) & 15;
            bf16x8 af = *(const bf16x8*)&emb_bf[row][g << 3];
            bf16x8 bfr[4];
#pragma unroll
            for (int i = 0; i < 4; ++i) {
                int n = (dtb + i) * 16 + l15;
                bfr[i] = *(const bf16x8*)(wb + (size_t)n * 384 + kk * 32 + kg * 8);
            }
#pragma unroll
            for (int i = 0; i < 4; ++i)
                acc[i] = __builtin_amdgcn_mfma_f32_16x16x32_bf16(af, bfr[i], acc[i], 0, 0, 0);
        }
#pragma unroll
        for (int i = 0; i < 4; ++i) {
            int dout = (dtb + i) * 16 + l15;
            float bias = (c ? bB : bA)[dout];
#pragma unroll
            for (int reg = 0; reg < 4; ++reg) {
                int lrow = kg * 4 + reg;
                if (lrow < 12) {
                    int r = c * 12 + lrow;
                    ctx_bf[r][swz(dout, r)] = f2b(acc[i][reg] + bias);
                }
            }
        }
    }
    __syncthreads();

    // ---- logits via MFMA: wave w -> Mtile mt = w&1, N-half nh = w>>1
    int mt = w & 1, nh = w >> 1;
    f32x4 lacc[16];
#pragma unroll
    for (int i = 0; i < 16; ++i) lacc[i] = (f32x4){0.f, 0.f, 0.f, 0.f};
    int arow = mt * 16 + l15;
#pragma unroll
    for (int kk = 0; kk < 4; ++kk) {
        int g = ((kk * 4 + kg) ^ (arow & 7)) & 15;
        bf16x8 af = *(const bf16x8*)&ctx_bf[arow][g << 3];
        const short* lb = g_lost_bf + kk * 32 + kg * 8;
        // batch-load all 16 B fragments (registers now available), then MFMA chain
        bf16x8 bfr[16];
#pragma unroll
        for (int i = 0; i < 16; ++i) {
            int n = (nh * 16 + i) * 16 + l15;
            bfr[i] = *(const bf16x8*)(lb + (size_t)n * 128);
        }
#pragma unroll
        for (int i = 0; i < 16; ++i)
            lacc[i] = __builtin_amdgcn_mfma_f32_16x16x32_bf16(af, bfr[i], lacc[i], 0, 0, 0);
    }

    // ---- softmax (rows r = mt*16 + kg*4 + reg; col halves split across wave pair)
    float fm[4], norm[4];
#pragma unroll
    for (int reg = 0; reg < 4; ++reg) {
        float m = lacc[0][reg];
#pragma unroll
        for (int i = 1; i < 16; ++i) m = fmaxf(m, lacc[i][reg]);
        for (int off = 1; off < 16; off <<= 1) m = fmaxf(m, __shfl_xor(m, off, 64));
        if (l15 == 0) redm[w][kg * 4 + reg] = m;
    }
    __syncthreads();
#pragma unroll
    for (int reg = 0; reg < 4; ++reg)
        fm[reg] = fmaxf(redm[w][kg * 4 + reg], redm[w ^ 2][kg * 4 + reg]);
#pragma unroll
    for (int reg = 0; reg < 4; ++reg) {
        float s = 0.f;
#pragma unroll
        for (int i = 0; i < 16; ++i) s += __expf(lacc[i][reg] - fm[reg]);
        for (int off = 1; off < 16; off <<= 1) s += __shfl_xor(s, off, 64);
        if (l15 == 0) reds[w][kg * 4 + reg] = s;
    }
    __syncthreads();
#pragma unroll
    for (int reg = 0; reg < 4; ++reg)
        norm[reg] = fm[reg] + __logf(reds[w][kg * 4 + reg] + reds[w ^ 2][kg * 4 + reg]);

    // ---- stage fragments into f32 LDS (aliases emb/ctx — all reads done)
#pragma unroll
    for (int reg = 0; reg < 4; ++reg) {
        int r = mt * 16 + kg * 4 + reg;
        if (r >= 24) continue;
        float nrm = norm[reg];
        bool isSub = (r < 12);
#pragma unroll
        for (int i = 0; i < 16; ++i) {
            int col = nh * 256 + i * 16 + l15;
            float lp = lacc[i][reg] - nrm;
            stage[r][col] = isSub ? (-CW * lp) : (IDC - CW * lp);
        }
    }
    __syncthreads();

    // ---- coalesced streaming output: float4 rows
#pragma unroll
    for (int j = 0; j < 6; ++j) {
        int idx = t + j * 256;
        int r = idx >> 7, q = idx & 127;
        float4 sv = *(const float4*)&stage[r][q * 4];
        const float4 gv = *(const float4*)(g_ulp + (size_t)sids[r] * LOST_ + q * 4);
        float4 o;
        o.x = sv.x - 0.5f * gv.x;
        o.y = sv.y - 0.5f * gv.y;
        o.z = sv.z - 0.5f * gv.z;
        o.w = sv.w - 0.5f * gv.w;
        *(float4*)&sub_out[((size_t)v * 12 + r) * 512 + q * 4] = o;
    }
#pragma unroll
    for (int j = 0; j < 6; ++j) {
        int idx = t + j * 256;
        int r = idx >> 7, q = idx & 127;
        float4 sv = *(const float4*)&stage[12 + r][q * 4];
        *(float4*)&ins_out[((size_t)v * 12 + r) * 512 + q * 4] = sv;
    }
}

extern "C" void kernel_launch(void* const* d_in, const int* in_sizes, int n_in,
                              void* d_out, int out_size, void* d_ws, size_t ws_size,
                              hipStream_t stream) {
    const float* E = (const float*)d_in[0];         // known_unit_emb [512][128]
    const float* W = (const float*)d_in[1];         // unit_aligner_weight [512][512]
    const float* convW = (const float*)d_in[2];     // [128][128][3]
    const float* convB = (const float*)d_in[3];     // [128]
    const float* insW = (const float*)d_in[4];
    const float* insB = (const float*)d_in[5];
    const int* ids = (const int*)d_in[6];           // [16000][12]
    const int* lens = (const int*)d_in[7];          // [16000]

    float* out = (float*)d_out;                                // FLOAT32 output
    float* sub_out = out;                                      // [V][L][512]
    float* ins_out = out + (size_t)V_ * L_ * LOST_;            // [V][L][512]
    float* align_out = out + 2ull * V_ * L_ * LOST_;           // [512][512]

    hipLaunchKernelGGL(k_wcv, dim3((2 * 128 * 384 + 255) / 256), dim3(256), 0, stream,
                       convW, insW);
    hipLaunchKernelGGL(k_lost, dim3(LOST_), dim3(128), 0, stream, W, E);
    hipLaunchKernelGGL(k_ulp, dim3(K_), dim3(512), 0, stream, E, align_out);
    hipLaunchKernelGGL(k_main, dim3(V_), dim3(256), 0, stream,
                       E, convB, insB, ids, lens, sub_out, ins_out);
}

// Round 24
// 434.887 us; speedup vs baseline: 2.0596x; 2.0596x over previous
//
#include <hip/hip_runtime.h>
#include <hip/hip_bf16.h>

#define V_ 16000
#define L_ 12
#define K_ 512
#define LOST_ 512
#define D_ 128

constexpr float CW = 0.5f;
constexpr float IDC = 3.5f;

typedef __attribute__((ext_vector_type(8))) short bf16x8;
typedef __attribute__((ext_vector_type(4))) float f32x4;

__device__ __align__(16) float g_lost[LOST_ * D_];    // lost_unit_emb f32 [512][128]
__device__ __align__(16) short g_lostF[LOST_ * D_];   // bf16 fragment-contiguous [ntile(32)][kk(4)][lane(64)][8]
__device__ __align__(16) float g_ulp[K_ * LOST_];     // unit_log_probs [512][512]
__device__ __align__(16) short g_wcvF[2 * 128 * 384]; // conv weights bf16 frag-contig [c][dtile(8)][kk(12)][lane(64)][8]

__device__ __forceinline__ short f2b(float x) {
    __hip_bfloat16 h = __float2bfloat16(x);
    return *reinterpret_cast<short*>(&h);
}

// ---------------- kernel 0: conv weights -> fragment-contiguous bf16
__global__ __launch_bounds__(256) void k_wcv(const float* __restrict__ wA,
                                             const float* __restrict__ wB) {
    int idx = blockIdx.x * 256 + threadIdx.x;       // (c,dout,t3,di) flat: ((c*128+dout)*3+t3)*128+di? keep orig decomp
    if (idx >= 2 * 128 * 384) return;
    int di = idx % 128;
    int t3 = (idx / 128) % 3;
    int dout = (idx / 384) % 128;
    int c = idx / (128 * 384);
    // fragment coords
    int dtile = dout >> 4, l15 = dout & 15;
    int kk = t3 * 4 + (di >> 5);
    int kg = (di >> 3) & 3;
    int j = di & 7;
    int lane = kg * 16 + l15;
    const float* w = c ? wB : wA;
    g_wcvF[(size_t)(((c * 8 + dtile) * 12 + kk) << 9) + lane * 8 + j] =
        f2b(w[((size_t)dout * 128 + di) * 3 + t3]);
}

// ---------------- kernel 1: lost_emb = aligner @ E (f32 + fragment-contiguous bf16)
__global__ __launch_bounds__(128) void k_lost(const float* __restrict__ W,
                                              const float* __restrict__ E) {
    int m = blockIdx.x;
    int d = threadIdx.x;
    const float* wrow = W + (size_t)m * K_;
    float acc = 0.f;
    for (int k = 0; k < K_; ++k) acc = fmaf(wrow[k], E[k * D_ + d], acc);
    g_lost[m * D_ + d] = acc;
    int ntile = m >> 4, l15 = m & 15;
    int kk = d >> 5, kg = (d >> 3) & 3, j = d & 7;
    int lane = kg * 16 + l15;
    g_lostF[(size_t)(((ntile << 2) + kk) << 9) + lane * 8 + j] = f2b(acc);
}

// ---------------- kernel 2: unit_log_probs + alignment output (f32)
__global__ __launch_bounds__(512) void k_ulp(const float* __restrict__ E,
                                             float* __restrict__ align_out) {
    int k = blockIdx.x, t = threadIdx.x;
    __shared__ float e[D_];
    __shared__ float red[8];
    if (t < D_) e[t] = E[k * D_ + t];
    __syncthreads();
    const float* lm = g_lost + (size_t)t * D_;
    float acc = 0.f;
    for (int d = 0; d < D_; d += 4) {
        float4 lv = *(const float4*)(lm + d);
        acc = fmaf(e[d], lv.x, acc);
        acc = fmaf(e[d + 1], lv.y, acc);
        acc = fmaf(e[d + 2], lv.z, acc);
        acc = fmaf(e[d + 3], lv.w, acc);
    }
    int lane = t & 63, wid = t >> 6;
    float wm = acc;
    for (int off = 32; off; off >>= 1) wm = fmaxf(wm, __shfl_xor(wm, off, 64));
    if (lane == 0) red[wid] = wm;
    __syncthreads();
    float bm = red[0];
#pragma unroll
    for (int i = 1; i < 8; ++i) bm = fmaxf(bm, red[i]);
    __syncthreads();
    float s = expf(acc - bm);
    for (int off = 32; off; off >>= 1) s += __shfl_xor(s, off, 64);
    if (lane == 0) red[wid] = s;
    __syncthreads();
    float bs = 0.f;
#pragma unroll
    for (int i = 0; i < 8; ++i) bs += red[i];
    float lp = acc - bm - logf(bs);
    g_ulp[(size_t)k * LOST_ + t] = lp;
    align_out[(size_t)k * LOST_ + t] = expf(lp);
}

// swizzled column: keep low 3 bits, XOR granule (bits 3..6) with row&7
__device__ __forceinline__ int swz(int col, int row) {
    return (col & 7) | ((((col >> 3) ^ (row & 7)) & 15) << 3);
}

// ---------------- kernel 3: fused MFMA per-v kernel
__global__ __launch_bounds__(256, 3) void k_main(const float* __restrict__ E,
                                                 const float* __restrict__ bA,
                                                 const float* __restrict__ bB,
                                                 const int* __restrict__ ids,
                                                 const int* __restrict__ lens,
                                                 float* __restrict__ sub_out,
                                                 float* __restrict__ ins_out) {
    __shared__ __align__(16) char shbuf[24 * 516 * 4];    // arena
    short (*emb_bf)[128] = (short(*)[128])shbuf;          // 18 rows
    short (*ctx_bf)[128] = (short(*)[128])(shbuf + 4608); // 32 rows
    float (*stage)[516] = (float(*)[516])shbuf;           // 24 f32 rows (epilogue)
    __shared__ float redm[4][16];
    __shared__ float reds[4][16];
    __shared__ int sids[12];
    __shared__ int slen;

    int v = blockIdx.x;
    int t = threadIdx.x;
    int lane = t & 63, w = t >> 6;
    int l15 = lane & 15, kg = lane >> 4;

    if (t < 12) sids[t] = min(max(ids[v * 12 + t], 0), 511);
    if (t == 12) slen = min(max(lens[v], 0), 12);
    for (int i = t; i < 8 * 128; i += 256) ctx_bf[24 + (i >> 7)][i & 127] = 0;
    __syncthreads();
    int len = slen;

    // ---- gather masked emb rows -> bf16 swizzled LDS
    for (int i = t; i < 18 * 128; i += 256) {
        int row = i >> 7, di = i & 127;
        float val = 0.f;
        if (row >= 1 && row <= 12) {
            int pos = row - 1;
            if (pos < len) val = E[(size_t)sids[pos] * D_ + di];
        }
        emb_bf[row][swz(di, row)] = f2b(val);
    }
    __syncthreads();

    // ---- conv via MFMA: wave w -> c = w&1, dout-tiles dtb..dtb+3
    {
        int c = w & 1;
        int dtb = (w >> 1) * 4;
        f32x4 acc[4];
#pragma unroll
        for (int i = 0; i < 4; ++i) acc[i] = (f32x4){0.f, 0.f, 0.f, 0.f};
#pragma unroll
        for (int kk = 0; kk < 12; ++kk) {
            int t3 = kk >> 2;
            int row = l15 + t3;
            int g = (((kk & 3) * 4 + kg) ^ (row & 7)) & 15;
            bf16x8 af = *(const bf16x8*)&emb_bf[row][g << 3];
            bf16x8 bfr[4];
#pragma unroll
            for (int i = 0; i < 4; ++i)
                bfr[i] = *(const bf16x8*)(g_wcvF +
                    ((size_t)(((c * 8 + dtb + i) * 12 + kk) << 9)) + lane * 8);
#pragma unroll
            for (int i = 0; i < 4; ++i)
                acc[i] = __builtin_amdgcn_mfma_f32_16x16x32_bf16(af, bfr[i], acc[i], 0, 0, 0);
        }
#pragma unroll
        for (int i = 0; i < 4; ++i) {
            int dout = (dtb + i) * 16 + l15;
            float bias = (c ? bB : bA)[dout];
#pragma unroll
            for (int reg = 0; reg < 4; ++reg) {
                int lrow = kg * 4 + reg;
                if (lrow < 12) {
                    int r = c * 12 + lrow;
                    ctx_bf[r][swz(dout, r)] = f2b(acc[i][reg] + bias);
                }
            }
        }
    }
    __syncthreads();

    // ---- logits via MFMA: wave w -> Mtile mt = w&1, N-half nh = w>>1
    int mt = w & 1, nh = w >> 1;
    f32x4 lacc[16];
#pragma unroll
    for (int i = 0; i < 16; ++i) lacc[i] = (f32x4){0.f, 0.f, 0.f, 0.f};
    int arow = mt * 16 + l15;
#pragma unroll
    for (int kk = 0; kk < 4; ++kk) {
        int g = ((kk * 4 + kg) ^ (arow & 7)) & 15;
        bf16x8 af = *(const bf16x8*)&ctx_bf[arow][g << 3];
        bf16x8 bfr[16];
#pragma unroll
        for (int i = 0; i < 16; ++i)
            bfr[i] = *(const bf16x8*)(g_lostF +
                ((size_t)((((nh * 16 + i) << 2) + kk) << 9)) + lane * 8);
#pragma unroll
        for (int i = 0; i < 16; ++i)
            lacc[i] = __builtin_amdgcn_mfma_f32_16x16x32_bf16(af, bfr[i], lacc[i], 0, 0, 0);
    }

    // ---- softmax (rows r = mt*16 + kg*4 + reg; col halves split across wave pair)
    float fm[4], norm[4];
#pragma unroll
    for (int reg = 0; reg < 4; ++reg) {
        float m = lacc[0][reg];
#pragma unroll
        for (int i = 1; i < 16; ++i) m = fmaxf(m, lacc[i][reg]);
        for (int off = 1; off < 16; off <<= 1) m = fmaxf(m, __shfl_xor(m, off, 64));
        if (l15 == 0) redm[w][kg * 4 + reg] = m;
    }
    __syncthreads();
#pragma unroll
    for (int reg = 0; reg < 4; ++reg)
        fm[reg] = fmaxf(redm[w][kg * 4 + reg], redm[w ^ 2][kg * 4 + reg]);
#pragma unroll
    for (int reg = 0; reg < 4; ++reg) {
        float s = 0.f;
#pragma unroll
        for (int i = 0; i < 16; ++i) s += __expf(lacc[i][reg] - fm[reg]);
        for (int off = 1; off < 16; off <<= 1) s += __shfl_xor(s, off, 64);
        if (l15 == 0) reds[w][kg * 4 + reg] = s;
    }
    __syncthreads();
#pragma unroll
    for (int reg = 0; reg < 4; ++reg)
        norm[reg] = fm[reg] + __logf(reds[w][kg * 4 + reg] + reds[w ^ 2][kg * 4 + reg]);

    // ---- stage fragments into f32 LDS (aliases emb/ctx — all reads done)
#pragma unroll
    for (int reg = 0; reg < 4; ++reg) {
        int r = mt * 16 + kg * 4 + reg;
        if (r >= 24) continue;
        float nrm = norm[reg];
        bool isSub = (r < 12);
#pragma unroll
        for (int i = 0; i < 16; ++i) {
            int col = nh * 256 + i * 16 + l15;
            float lp = lacc[i][reg] - nrm;
            stage[r][col] = isSub ? (-CW * lp) : (IDC - CW * lp);
        }
    }
    __syncthreads();

    // ---- coalesced streaming output: float4 rows
#pragma unroll
    for (int j = 0; j < 6; ++j) {
        int idx = t + j * 256;
        int r = idx >> 7, q = idx & 127;
        float4 sv = *(const float4*)&stage[r][q * 4];
        const float4 gv = *(const float4*)(g_ulp + (size_t)sids[r] * LOST_ + q * 4);
        float4 o;
        o.x = sv.x - 0.5f * gv.x;
        o.y = sv.y - 0.5f * gv.y;
        o.z = sv.z - 0.5f * gv.z;
        o.w = sv.w - 0.5f * gv.w;
        *(float4*)&sub_out[((size_t)v * 12 + r) * 512 + q * 4] = o;
    }
#pragma unroll
    for (int j = 0; j < 6; ++j) {
        int idx = t + j * 256;
        int r = idx >> 7, q = idx & 127;
        float4 sv = *(const float4*)&stage[12 + r][q * 4];
        *(float4*)&ins_out[((size_t)v * 12 + r) * 512 + q * 4] = sv;
    }
}

extern "C" void kernel_launch(void* const* d_in, const int* in_sizes, int n_in,
                              void* d_out, int out_size, void* d_ws, size_t ws_size,
                              hipStream_t stream) {
    const float* E = (const float*)d_in[0];         // known_unit_emb [512][128]
    const float* W = (const float*)d_in[1];         // unit_aligner_weight [512][512]
    const float* convW = (const float*)d_in[2];     // [128][128][3]
    const float* convB = (const float*)d_in[3];     // [128]
    const float* insW = (const float*)d_in[4];
    const float* insB = (const float*)d_in[5];
    const int* ids = (const int*)d_in[6];           // [16000][12]
    const int* lens = (const int*)d_in[7];          // [16000]

    float* out = (float*)d_out;                                // FLOAT32 output
    float* sub_out = out;                                      // [V][L][512]
    float* ins_out = out + (size_t)V_ * L_ * LOST_;            // [V][L][512]
    float* align_out = out + 2ull * V_ * L_ * LOST_;           // [512][512]

    hipLaunchKernelGGL(k_wcv, dim3((2 * 128 * 384 + 255) / 256), dim3(256), 0, stream,
                       convW, insW);
    hipLaunchKernelGGL(k_lost, dim3(LOST_), dim3(128), 0, stream, W, E);
    hipLaunchKernelGGL(k_ulp, dim3(K_), dim3(512), 0, stream, E, align_out);
    hipLaunchKernelGGL(k_main, dim3(V_), dim3(256), 0, stream,
                       E, convB, insB, ids, lens, sub_out, ins_out);
}